// Round 5
// baseline (716.865 us; speedup 1.0000x reference)
//
#include <hip/hip_runtime.h>

// DIAGNOSTIC ROUND: identical kernel to round 4, but launched 4x per call to
// measure kernel-proper duration via dur_us delta: K = (dur - 434)/3.
// Kernel is idempotent (pure permutation in -> out), so repeated launches
// produce the identical output and are graph-capture safe.

#define HWDIM  128
#define BCNT   32
#define CHALF  64
#define TILE   64

__global__ __launch_bounds__(256) void shuffle_aug_kernel(
    const float* __restrict__ x1,
    const float* __restrict__ x2,
    const int*   __restrict__ flips,   // (5, 32) int32
    float*       __restrict__ out)
{
    __shared__ float lds[TILE][TILE + 1];   // +1 pad: column reads conflict-light

    const int bid  = blockIdx.x;
    const int tile = bid & 3;              // 2x2 tiles of the plane
    const int ct   = (bid >> 2) & 127;     // concatenated channel
    const int b    = bid >> 9;             // sample

    const int f0 = flips[0 * BCNT + b];
    const int f1 = flips[1 * BCNT + b];
    const int f2 = flips[2 * BCNT + b];    // swap
    const int f3 = flips[3 * BCNT + b];
    const int f4 = flips[4 * BCNT + b];

    const bool swp  = (f2 != 0);
    const bool revA = ((swp ? (f0 ^ f4) : (f0 ^ f3)) != 0);  // row-source reversed
    const bool revC = ((swp ? (f1 ^ f3) : (f1 ^ f4)) != 0);  // col-source reversed

    const int i0 = (tile >> 1) * TILE;     // output tile origin
    const int j0 = (tile & 1) * TILE;

    const int cLoc = ct & (CHALF - 1);
    const size_t plane = (size_t)(b * CHALF + cLoc) * (HWDIM * HWDIM);
    const float4* __restrict__ src4 =
        reinterpret_cast<const float4*>(((ct < CHALF) ? x1 : x2) + plane);
    float4* __restrict__ dst4 = reinterpret_cast<float4*>(
        out + ((ct < CHALF) ? (size_t)0 : (size_t)BCNT * CHALF * HWDIM * HWDIM) + plane);

    const int t = threadIdx.x;

    if (!swp) {
        // ---- direct copy: out[i][j] = in[rA(i)][rC(j)] ----
#pragma unroll
        for (int p = 0; p < 4; ++p) {
            const int d   = p * 256 + t;
            const int ir  = d >> 4;                 // 0..63 tile row
            const int jf4 = d & 15;                 // 0..15 tile f4-col
            const int i   = i0 + ir;
            const int a   = revA ? 127 - i : i;
            const int cf4 = revC ? (31 - (j0 >> 2) - jf4) : ((j0 >> 2) + jf4);
            float4 v = src4[a * 32 + cf4];
            if (revC) { float x = v.x; v.x = v.w; v.w = x;
                        float y = v.y; v.y = v.z; v.z = y; }
            dst4[i * 32 + (j0 >> 2) + jf4] = v;
        }
    } else {
        // ---- transpose: out[i][j] = in[rA(j)][rC(i)] ----
        const int aMin = revA ? (TILE - j0) : j0;
        const int cMin = revC ? (TILE - i0) : i0;

#pragma unroll
        for (int p = 0; p < 4; ++p) {
            const int d  = p * 256 + t;
            const int r  = d >> 4;                  // 0..63 source row offset
            const int c4 = d & 15;                  // 0..15 source f4-col
            float4 v = src4[(aMin + r) * 32 + (cMin >> 2) + c4];
            lds[r][c4 * 4 + 0] = v.x;
            lds[r][c4 * 4 + 1] = v.y;
            lds[r][c4 * 4 + 2] = v.z;
            lds[r][c4 * 4 + 3] = v.w;
        }
        __syncthreads();

#pragma unroll
        for (int p = 0; p < 4; ++p) {
            const int d   = p * 256 + t;
            const int ir  = d >> 4;
            const int jf4 = d & 15;
            const int i   = i0 + ir;
            const int c   = (revC ? 127 - i : i) - cMin;
            float ov[4];
#pragma unroll
            for (int e = 0; e < 4; ++e) {
                const int j = j0 + 4 * jf4 + e;
                const int a = (revA ? 127 - j : j) - aMin;
                ov[e] = lds[a][c];
            }
            dst4[i * 32 + (j0 >> 2) + jf4] = make_float4(ov[0], ov[1], ov[2], ov[3]);
        }
    }
}

extern "C" void kernel_launch(void* const* d_in, const int* in_sizes, int n_in,
                              void* d_out, int out_size, void* d_ws, size_t ws_size,
                              hipStream_t stream) {
    const float* x1    = (const float*)d_in[0];
    const float* x2    = (const float*)d_in[1];
    const int*   flips = (const int*)d_in[2];
    float*       out   = (float*)d_out;

    const int grid = BCNT * 2 * CHALF * 4;   // 16384 tiles
    // 4 identical idempotent launches: dur_us = fixed + 4*K -> measures K.
    for (int rep = 0; rep < 4; ++rep) {
        shuffle_aug_kernel<<<grid, 256, 0, stream>>>(x1, x2, flips, out);
    }
}

// Round 6
// 432.824 us; speedup vs baseline: 1.6563x; 1.6563x over previous
//
#include <hip/hip_runtime.h>

// shuffleAug: 5 chained per-sample gathers compose to one affine map
//   out[i][j] = in[rA(i)][rC(j)]            (no swap)
//   out[i][j] = in[rA(j)][rC(i)]            (swap)
// where rA/rC are identity or (127 - idx), derived from the 5 flip bits.
// One 64x64 output tile per block (grid 16384, 256 thr):
//  - LDS 64x65 floats (16.6 KiB) -> 8 blocks/CU -> full 32-wave occupancy
//  - non-swap blocks: direct streaming copy, no LDS, no barrier
//  - swap blocks: coalesced load -> padded-LDS transpose -> coalesced store
// Measured (round-5 4x-launch diagnostic): kernel-proper = 94.3 us for
// 537 MB R+W = 5.7 TB/s = 91% of the 6.29 TB/s float4-copy ceiling -> at
// the memory roofline. dur_us ~434 = ~340 us fixed harness reset + kernel.

#define HWDIM  128
#define BCNT   32
#define CHALF  64
#define TILE   64

__global__ __launch_bounds__(256) void shuffle_aug_kernel(
    const float* __restrict__ x1,
    const float* __restrict__ x2,
    const int*   __restrict__ flips,   // (5, 32) int32
    float*       __restrict__ out)
{
    __shared__ float lds[TILE][TILE + 1];   // +1 pad: column reads conflict-light

    const int bid  = blockIdx.x;
    const int tile = bid & 3;              // 2x2 tiles of the plane
    const int ct   = (bid >> 2) & 127;     // concatenated channel
    const int b    = bid >> 9;             // sample

    const int f0 = flips[0 * BCNT + b];
    const int f1 = flips[1 * BCNT + b];
    const int f2 = flips[2 * BCNT + b];    // swap
    const int f3 = flips[3 * BCNT + b];
    const int f4 = flips[4 * BCNT + b];

    const bool swp  = (f2 != 0);
    const bool revA = ((swp ? (f0 ^ f4) : (f0 ^ f3)) != 0);  // row-source reversed
    const bool revC = ((swp ? (f1 ^ f3) : (f1 ^ f4)) != 0);  // col-source reversed

    const int i0 = (tile >> 1) * TILE;     // output tile origin
    const int j0 = (tile & 1) * TILE;

    const int cLoc = ct & (CHALF - 1);
    const size_t plane = (size_t)(b * CHALF + cLoc) * (HWDIM * HWDIM);
    const float4* __restrict__ src4 =
        reinterpret_cast<const float4*>(((ct < CHALF) ? x1 : x2) + plane);
    float4* __restrict__ dst4 = reinterpret_cast<float4*>(
        out + ((ct < CHALF) ? (size_t)0 : (size_t)BCNT * CHALF * HWDIM * HWDIM) + plane);

    const int t = threadIdx.x;

    if (!swp) {
        // ---- direct copy: out[i][j] = in[rA(i)][rC(j)] ----
#pragma unroll
        for (int p = 0; p < 4; ++p) {
            const int d   = p * 256 + t;
            const int ir  = d >> 4;                 // 0..63 tile row
            const int jf4 = d & 15;                 // 0..15 tile f4-col
            const int i   = i0 + ir;
            const int a   = revA ? 127 - i : i;
            const int cf4 = revC ? (31 - (j0 >> 2) - jf4) : ((j0 >> 2) + jf4);
            float4 v = src4[a * 32 + cf4];
            if (revC) { float x = v.x; v.x = v.w; v.w = x;
                        float y = v.y; v.y = v.z; v.z = y; }
            dst4[i * 32 + (j0 >> 2) + jf4] = v;
        }
    } else {
        // ---- transpose: out[i][j] = in[rA(j)][rC(i)] ----
        const int aMin = revA ? (TILE - j0) : j0;
        const int cMin = revC ? (TILE - i0) : i0;

#pragma unroll
        for (int p = 0; p < 4; ++p) {
            const int d  = p * 256 + t;
            const int r  = d >> 4;                  // 0..63 source row offset
            const int c4 = d & 15;                  // 0..15 source f4-col
            float4 v = src4[(aMin + r) * 32 + (cMin >> 2) + c4];
            lds[r][c4 * 4 + 0] = v.x;
            lds[r][c4 * 4 + 1] = v.y;
            lds[r][c4 * 4 + 2] = v.z;
            lds[r][c4 * 4 + 3] = v.w;
        }
        __syncthreads();

#pragma unroll
        for (int p = 0; p < 4; ++p) {
            const int d   = p * 256 + t;
            const int ir  = d >> 4;
            const int jf4 = d & 15;
            const int i   = i0 + ir;
            const int c   = (revC ? 127 - i : i) - cMin;
            float ov[4];
#pragma unroll
            for (int e = 0; e < 4; ++e) {
                const int j = j0 + 4 * jf4 + e;
                const int a = (revA ? 127 - j : j) - aMin;
                ov[e] = lds[a][c];
            }
            dst4[i * 32 + (j0 >> 2) + jf4] = make_float4(ov[0], ov[1], ov[2], ov[3]);
        }
    }
}

extern "C" void kernel_launch(void* const* d_in, const int* in_sizes, int n_in,
                              void* d_out, int out_size, void* d_ws, size_t ws_size,
                              hipStream_t stream) {
    const float* x1    = (const float*)d_in[0];
    const float* x2    = (const float*)d_in[1];
    const int*   flips = (const int*)d_in[2];
    float*       out   = (float*)d_out;

    const int grid = BCNT * 2 * CHALF * 4;   // 32 * 128 * 4 = 16384 tiles
    shuffle_aug_kernel<<<grid, 256, 0, stream>>>(x1, x2, flips, out);
}